// Round 2
// baseline (136.986 us; speedup 1.0000x reference)
//
#include <hip/hip_runtime.h>

// MLS warp: B batches, C=68 control points, 32x32 grid, fp32.
// Single-pass centered-moment formulation:
//   dx_c = pf_c - v          (pf = dp coord-swapped; center p at pixel v)
//   accumulate: wsum, s=SUM(w dx), sq=SUM(w qf), m=SUM(w dx dx^T), k=SUM(w dx qf^T)
//   dxs = s/wsum  (== p* - v, so u = v - p* = -dxs)
//   M = m - dxs s^T   (centered covariance; no big-magnitude cancellation
//                      because weights concentrate where |dx| is small)
//   K = k - dxs sq^T  (SUM w h e^T, using SUM(w h) == 0 identity)
//   g = -dxs^T M^-1 ;  t = g^T K + sq/wsum ;  zero where t<0 or t>31.
#define NC 68

__global__ __launch_bounds__(256, 8) void mls_kernel(
    const float* __restrict__ sp, const float* __restrict__ dp,
    float* __restrict__ out)
{
  const int b   = blockIdx.x >> 2;
  const int pix = ((blockIdx.x & 3) << 8) | threadIdx.x;   // 0..1023
  const float vx = (float)(pix & 31);   // column index j  (v[0])
  const float vy = (float)(pix >> 5);   // row index i     (v[1])

  // Block-uniform base pointers -> scalar (s_load) reads, shared by the wave.
  const float* __restrict__ spb = sp + b * (NC * 2);
  const float* __restrict__ dpb = dp + b * (NC * 2);

  float wsum = 0.f;
  float sx0 = 0.f, sx1 = 0.f;            // SUM w dx
  float sq0 = 0.f, sq1 = 0.f;            // SUM w qf
  float m00 = 0.f, m01 = 0.f, m11 = 0.f; // SUM w dx dx^T (symmetric)
  float k00 = 0.f, k01 = 0.f, k10 = 0.f, k11 = 0.f; // SUM w dx qf^T

#pragma unroll
  for (int c = 0; c < NC; ++c) {
    // coord swap: pf[:,0]=dp[:,1], pf[:,1]=dp[:,0]; same for qf/sp.
    // (.astype(int16) in ref is identity: inputs are exact ints 0..31)
    const float pf0 = dpb[2 * c + 1];
    const float pf1 = dpb[2 * c + 0];
    const float qf0 = spb[2 * c + 1];
    const float qf1 = spb[2 * c + 0];
    const float dx = pf0 - vx, dy = pf1 - vy;
    const float d2 = fmaf(dy, dy, fmaf(dx, dx, 1e-8f));
    // fast reciprocal + 1 Newton step (~1 ulp) instead of IEEE div sequence
    float r = __builtin_amdgcn_rcpf(d2);
    r = r * fmaf(-d2, r, 2.0f);
    const float wc = r;
    wsum += wc;
    const float wdx = wc * dx, wdy = wc * dy;
    sx0 += wdx; sx1 += wdy;
    sq0 = fmaf(wc, qf0, sq0); sq1 = fmaf(wc, qf1, sq1);
    m00 = fmaf(wdx, dx, m00); m01 = fmaf(wdx, dy, m01); m11 = fmaf(wdy, dy, m11);
    k00 = fmaf(wdx, qf0, k00); k01 = fmaf(wdx, qf1, k01);
    k10 = fmaf(wdy, qf0, k10); k11 = fmaf(wdy, qf1, k11);
  }

  // Epilogue (once per thread; IEEE divides kept for numeric fidelity).
  const float rw = 1.0f / wsum;
  const float dxs0 = sx0 * rw, dxs1 = sx1 * rw;   // p* - v
  const float qs0 = sq0 * rw, qs1 = sq1 * rw;     // q*
  // centered 2x2 covariance and cross matrix
  const float M00 = fmaf(-dxs0, sx0, m00);
  const float M01 = fmaf(-dxs0, sx1, m01);
  const float M11 = fmaf(-dxs1, sx1, m11);
  const float K00 = fmaf(-dxs0, sq0, k00);
  const float K01 = fmaf(-dxs0, sq1, k01);
  const float K10 = fmaf(-dxs1, sq0, k10);
  const float K11 = fmaf(-dxs1, sq1, k11);
  // g = u^T M^-1 with u = -dxs
  const float det  = fmaf(M00, M11, -M01 * M01);
  const float idet = 1.0f / det;
  const float g0 = -(dxs0 * M11 - dxs1 * M01) * idet;
  const float g1 = -(dxs1 * M00 - dxs0 * M01) * idet;
  float t0 = fmaf(g0, K00, fmaf(g1, K10, qs0));
  float t1 = fmaf(g0, K01, fmaf(g1, K11, qs1));

  // Out-of-range pixels zeroed (NOT clipped), matching reference.
  if (t0 < 0.f || t0 > 31.f) t0 = 0.f;
  if (t1 < 0.f || t1 > 31.f) t1 = 0.f;

  // out layout (B, 2, 32, 32)
  out[b * 2048 + pix]        = t0;
  out[b * 2048 + 1024 + pix] = t1;
}

extern "C" void kernel_launch(void* const* d_in, const int* in_sizes, int n_in,
                              void* d_out, int out_size, void* d_ws, size_t ws_size,
                              hipStream_t stream) {
  const float* sp = (const float*)d_in[0];
  const float* dp = (const float*)d_in[1];
  float* out = (float*)d_out;
  const int B = in_sizes[0] / (NC * 2);   // 512
  mls_kernel<<<dim3(B * 4), dim3(256), 0, stream>>>(sp, dp, out);
}

// Round 3
// 74.669 us; speedup vs baseline: 1.8346x; 1.8346x over previous
//
#include <hip/hip_runtime.h>

// MLS warp: B batches, C=68 control points, 32x32 grid, fp32.
// Single-pass centered-moment formulation:
//   dx_c = pf_c - v          (pf = dp coord-swapped; center p at pixel v)
//   accumulate: wsum, s=SUM(w dx), sq=SUM(w qf), m=SUM(w dx dx^T), k=SUM(w dx qf^T)
//   dxs = s/wsum  (== p* - v, so u = v - p* = -dxs)
//   M = m - dxs s^T   (centered covariance; no big-magnitude cancellation
//                      because weights concentrate where |dx| is small)
//   K = k - dxs sq^T  (SUM w h e^T, using SUM(w h) == 0 identity)
//   g = -dxs^T M^-1 ;  t = g^T K + sq/wsum ;  zero where t<0 or t>31.
//
// R2 lesson: __launch_bounds__(256,8) clamped VGPR to 32 and spilled the
// accumulators (235 MB scratch writes/launch). Plain bound: natural ~40-80
// VGPR, no spill, 6-8 waves/SIMD.
#define NC 68

__global__ __launch_bounds__(256) void mls_kernel(
    const float* __restrict__ sp, const float* __restrict__ dp,
    float* __restrict__ out)
{
  const int b   = blockIdx.x >> 2;
  const int pix = ((blockIdx.x & 3) << 8) | threadIdx.x;   // 0..1023
  const float vx = (float)(pix & 31);   // column index j  (v[0])
  const float vy = (float)(pix >> 5);   // row index i     (v[1])

  // Block-uniform base pointers -> scalar (s_load) reads, shared by the wave.
  const float* __restrict__ spb = sp + b * (NC * 2);
  const float* __restrict__ dpb = dp + b * (NC * 2);

  float wsum = 0.f;
  float sx0 = 0.f, sx1 = 0.f;            // SUM w dx
  float sq0 = 0.f, sq1 = 0.f;            // SUM w qf
  float m00 = 0.f, m01 = 0.f, m11 = 0.f; // SUM w dx dx^T (symmetric)
  float k00 = 0.f, k01 = 0.f, k10 = 0.f, k11 = 0.f; // SUM w dx qf^T

#pragma unroll
  for (int c = 0; c < NC; ++c) {
    // coord swap: pf[:,0]=dp[:,1], pf[:,1]=dp[:,0]; same for qf/sp.
    // (.astype(int16) in ref is identity: inputs are exact ints 0..31)
    const float pf0 = dpb[2 * c + 1];
    const float pf1 = dpb[2 * c + 0];
    const float qf0 = spb[2 * c + 1];
    const float qf1 = spb[2 * c + 0];
    const float dx = pf0 - vx, dy = pf1 - vy;
    const float d2 = fmaf(dy, dy, fmaf(dx, dx, 1e-8f));
    // fast reciprocal + 1 Newton step (~1 ulp) instead of IEEE div sequence
    float r = __builtin_amdgcn_rcpf(d2);
    r = r * fmaf(-d2, r, 2.0f);
    const float wc = r;
    wsum += wc;
    const float wdx = wc * dx, wdy = wc * dy;
    sx0 += wdx; sx1 += wdy;
    sq0 = fmaf(wc, qf0, sq0); sq1 = fmaf(wc, qf1, sq1);
    m00 = fmaf(wdx, dx, m00); m01 = fmaf(wdx, dy, m01); m11 = fmaf(wdy, dy, m11);
    k00 = fmaf(wdx, qf0, k00); k01 = fmaf(wdx, qf1, k01);
    k10 = fmaf(wdy, qf0, k10); k11 = fmaf(wdy, qf1, k11);
  }

  // Epilogue (once per thread; IEEE divides kept for numeric fidelity).
  const float rw = 1.0f / wsum;
  const float dxs0 = sx0 * rw, dxs1 = sx1 * rw;   // p* - v
  const float qs0 = sq0 * rw, qs1 = sq1 * rw;     // q*
  // centered 2x2 covariance and cross matrix
  const float M00 = fmaf(-dxs0, sx0, m00);
  const float M01 = fmaf(-dxs0, sx1, m01);
  const float M11 = fmaf(-dxs1, sx1, m11);
  const float K00 = fmaf(-dxs0, sq0, k00);
  const float K01 = fmaf(-dxs0, sq1, k01);
  const float K10 = fmaf(-dxs1, sq0, k10);
  const float K11 = fmaf(-dxs1, sq1, k11);
  // g = u^T M^-1 with u = -dxs
  const float det  = fmaf(M00, M11, -M01 * M01);
  const float idet = 1.0f / det;
  const float g0 = -(dxs0 * M11 - dxs1 * M01) * idet;
  const float g1 = -(dxs1 * M00 - dxs0 * M01) * idet;
  float t0 = fmaf(g0, K00, fmaf(g1, K10, qs0));
  float t1 = fmaf(g0, K01, fmaf(g1, K11, qs1));

  // Out-of-range pixels zeroed (NOT clipped), matching reference.
  if (t0 < 0.f || t0 > 31.f) t0 = 0.f;
  if (t1 < 0.f || t1 > 31.f) t1 = 0.f;

  // out layout (B, 2, 32, 32)
  out[b * 2048 + pix]        = t0;
  out[b * 2048 + 1024 + pix] = t1;
}

extern "C" void kernel_launch(void* const* d_in, const int* in_sizes, int n_in,
                              void* d_out, int out_size, void* d_ws, size_t ws_size,
                              hipStream_t stream) {
  const float* sp = (const float*)d_in[0];
  const float* dp = (const float*)d_in[1];
  float* out = (float*)d_out;
  const int B = in_sizes[0] / (NC * 2);   // 512
  mls_kernel<<<dim3(B * 4), dim3(256), 0, stream>>>(sp, dp, out);
}

// Round 4
// 71.347 us; speedup vs baseline: 1.9200x; 1.0466x over previous
//
#include <hip/hip_runtime.h>

// MLS warp: B batches, C=68 control points, 32x32 grid, fp32.
// Single-pass centered-moment formulation (see R2/R3 notes):
//   dx_c = pf_c - v; accumulate wsum, s=SUM(w dx), sq=SUM(w qf),
//   m=SUM(w dx dx^T), k=SUM(w dx qf^T); M = m - dxs s^T, K = k - dxs sq^T,
//   g = -dxs^T M^-1, t = g^T K + q*; zero where t<0 or t>31.
//
// R2 lesson: __launch_bounds__(256,8) forced VGPR=32 -> accumulator spill
//   (235 MB scratch/launch). Plain bound only.
// R4 change: control points staged once per block into LDS, pre-swizzled as
//   float4 [pf0,pf1,qf0,qf1]. The unrolled c-loop reads one wave-uniform
//   ds_read_b128 per c (broadcast, conflict-free, deep lgkm pipelining)
//   instead of interleaved s_load chunks + lgkm waits (272 uniform dwords
//   didn't fit the SGPR file -> compiler stalled on scalar-load waits).
#define NC 68

__global__ __launch_bounds__(256) void mls_kernel(
    const float* __restrict__ sp, const float* __restrict__ dp,
    float* __restrict__ out)
{
  const int b   = blockIdx.x >> 2;
  const int pix = ((blockIdx.x & 3) << 8) | threadIdx.x;   // 0..1023
  const float vx = (float)(pix & 31);   // column index j  (v[0])
  const float vy = (float)(pix >> 5);   // row index i     (v[1])

  // Stage control points for this batch into LDS, swizzled:
  // ctrl[c] = (pf0, pf1, qf0, qf1) = (dp[2c+1], dp[2c], sp[2c+1], sp[2c]).
  // (.astype(int16) in ref is identity: inputs are exact ints 0..31)
  __shared__ float4 ctrl[NC];
  {
    const int t = threadIdx.x;
    if (t < NC) {
      const float2 dv = ((const float2*)(dp + b * (NC * 2)))[t];
      const float2 sv = ((const float2*)(sp + b * (NC * 2)))[t];
      ctrl[t] = make_float4(dv.y, dv.x, sv.y, sv.x);
    }
  }
  __syncthreads();

  float wsum = 0.f;
  float sx0 = 0.f, sx1 = 0.f;            // SUM w dx
  float sq0 = 0.f, sq1 = 0.f;            // SUM w qf
  float m00 = 0.f, m01 = 0.f, m11 = 0.f; // SUM w dx dx^T (symmetric)
  float k00 = 0.f, k01 = 0.f, k10 = 0.f, k11 = 0.f; // SUM w dx qf^T

#pragma unroll
  for (int c = 0; c < NC; ++c) {
    const float4 f = ctrl[c];            // one ds_read_b128, wave-uniform
    const float dx = f.x - vx, dy = f.y - vy;
    const float d2 = fmaf(dy, dy, fmaf(dx, dx, 1e-8f));
    // fast reciprocal + 1 Newton step (~0.5 ulp) instead of IEEE div
    float r = __builtin_amdgcn_rcpf(d2);
    r = r * fmaf(-d2, r, 2.0f);
    const float wc = r;
    wsum += wc;
    const float wdx = wc * dx, wdy = wc * dy;
    sx0 += wdx; sx1 += wdy;
    sq0 = fmaf(wc, f.z, sq0); sq1 = fmaf(wc, f.w, sq1);
    m00 = fmaf(wdx, dx, m00); m01 = fmaf(wdx, dy, m01); m11 = fmaf(wdy, dy, m11);
    k00 = fmaf(wdx, f.z, k00); k01 = fmaf(wdx, f.w, k01);
    k10 = fmaf(wdy, f.z, k10); k11 = fmaf(wdy, f.w, k11);
  }

  // Epilogue (once per thread; IEEE divides kept for numeric fidelity).
  const float rw = 1.0f / wsum;
  const float dxs0 = sx0 * rw, dxs1 = sx1 * rw;   // p* - v
  const float qs0 = sq0 * rw, qs1 = sq1 * rw;     // q*
  const float M00 = fmaf(-dxs0, sx0, m00);
  const float M01 = fmaf(-dxs0, sx1, m01);
  const float M11 = fmaf(-dxs1, sx1, m11);
  const float K00 = fmaf(-dxs0, sq0, k00);
  const float K01 = fmaf(-dxs0, sq1, k01);
  const float K10 = fmaf(-dxs1, sq0, k10);
  const float K11 = fmaf(-dxs1, sq1, k11);
  const float det  = fmaf(M00, M11, -M01 * M01);
  const float idet = 1.0f / det;
  const float g0 = -(dxs0 * M11 - dxs1 * M01) * idet;
  const float g1 = -(dxs1 * M00 - dxs0 * M01) * idet;
  float t0 = fmaf(g0, K00, fmaf(g1, K10, qs0));
  float t1 = fmaf(g0, K01, fmaf(g1, K11, qs1));

  // Out-of-range pixels zeroed (NOT clipped), matching reference.
  if (t0 < 0.f || t0 > 31.f) t0 = 0.f;
  if (t1 < 0.f || t1 > 31.f) t1 = 0.f;

  // out layout (B, 2, 32, 32)
  out[b * 2048 + pix]        = t0;
  out[b * 2048 + 1024 + pix] = t1;
}

extern "C" void kernel_launch(void* const* d_in, const int* in_sizes, int n_in,
                              void* d_out, int out_size, void* d_ws, size_t ws_size,
                              hipStream_t stream) {
  const float* sp = (const float*)d_in[0];
  const float* dp = (const float*)d_in[1];
  float* out = (float*)d_out;
  const int B = in_sizes[0] / (NC * 2);   // 512
  mls_kernel<<<dim3(B * 4), dim3(256), 0, stream>>>(sp, dp, out);
}

// Round 5
// 71.343 us; speedup vs baseline: 1.9201x; 1.0001x over previous
//
#include <hip/hip_runtime.h>

// MLS warp: B batches, C=68 control points, 32x32 grid, fp32.
// Single-pass centered-moment formulation (see R2/R3 notes):
//   dx_c = pf_c - v; accumulate wsum, s=SUM(w dx), sq=SUM(w qf),
//   m=SUM(w dx dx^T), k=SUM(w dx qf^T); M = m - dxs s^T, K = k - dxs sq^T,
//   g = -dxs^T M^-1, t = g^T K + q*; zero where t<0 or t>31.
//
// R2 lesson: __launch_bounds__(256,8) forced VGPR=32 -> accumulator spill.
// R4 lesson: LDS staging of control points worth only ~3 us -> kernel is
//   latency-bound, not uniform-load-bound.
// R5 change: 2 pixels/thread, vertically paired (pix, pix+256: same column,
//   rows i and i+8). Shares dx and fmaf(dx,dx,1e-8) bit-identically, halves
//   ds_read per pixel, doubles independent FMA chains per wave (ILP 2x).
#define NC 68

__global__ __launch_bounds__(256) void mls_kernel(
    const float* __restrict__ sp, const float* __restrict__ dp,
    float* __restrict__ out)
{
  const int b = blockIdx.x >> 1;
  const int h = blockIdx.x & 1;                 // image half
  const int pixA = (h << 9) | threadIdx.x;      // rows 0..7   (h=0) / 16..23
  // pixB = pixA + 256 -> same column, row + 8
  const float vx  = (float)(pixA & 31);         // column j (shared)
  const float vyA = (float)(pixA >> 5);         // row i
  const float vyB = vyA + 8.0f;

  // Stage control points for this batch into LDS, swizzled:
  // ctrl[c] = (pf0, pf1, qf0, qf1) = (dp[2c+1], dp[2c], sp[2c+1], sp[2c]).
  // (.astype(int16) in ref is identity: inputs are exact ints 0..31)
  __shared__ float4 ctrl[NC];
  {
    const int t = threadIdx.x;
    if (t < NC) {
      const float2 dv = ((const float2*)(dp + b * (NC * 2)))[t];
      const float2 sv = ((const float2*)(sp + b * (NC * 2)))[t];
      ctrl[t] = make_float4(dv.y, dv.x, sv.y, sv.x);
    }
  }
  __syncthreads();

  // Pixel-A accumulators
  float wsA = 0.f, sxA0 = 0.f, sxA1 = 0.f, sqA0 = 0.f, sqA1 = 0.f;
  float mA00 = 0.f, mA01 = 0.f, mA11 = 0.f;
  float kA00 = 0.f, kA01 = 0.f, kA10 = 0.f, kA11 = 0.f;
  // Pixel-B accumulators
  float wsB = 0.f, sxB0 = 0.f, sxB1 = 0.f, sqB0 = 0.f, sqB1 = 0.f;
  float mB00 = 0.f, mB01 = 0.f, mB11 = 0.f;
  float kB00 = 0.f, kB01 = 0.f, kB10 = 0.f, kB11 = 0.f;

#pragma unroll
  for (int c = 0; c < NC; ++c) {
    const float4 f = ctrl[c];              // one wave-uniform ds_read_b128
    const float dx = f.x - vx;             // shared: same column
    const float e  = fmaf(dx, dx, 1e-8f);  // shared, bit-identical to R4
    // --- pixel A ---
    {
      const float dy = f.y - vyA;
      const float d2 = fmaf(dy, dy, e);
      float r = __builtin_amdgcn_rcpf(d2);
      r = r * fmaf(-d2, r, 2.0f);          // 1 Newton step (~0.5 ulp)
      const float wc = r;
      wsA += wc;
      const float wdx = wc * dx, wdy = wc * dy;
      sxA0 += wdx; sxA1 += wdy;
      sqA0 = fmaf(wc, f.z, sqA0); sqA1 = fmaf(wc, f.w, sqA1);
      mA00 = fmaf(wdx, dx, mA00); mA01 = fmaf(wdx, dy, mA01); mA11 = fmaf(wdy, dy, mA11);
      kA00 = fmaf(wdx, f.z, kA00); kA01 = fmaf(wdx, f.w, kA01);
      kA10 = fmaf(wdy, f.z, kA10); kA11 = fmaf(wdy, f.w, kA11);
    }
    // --- pixel B (independent chain; doubles ILP) ---
    {
      const float dy = f.y - vyB;
      const float d2 = fmaf(dy, dy, e);
      float r = __builtin_amdgcn_rcpf(d2);
      r = r * fmaf(-d2, r, 2.0f);
      const float wc = r;
      wsB += wc;
      const float wdx = wc * dx, wdy = wc * dy;
      sxB0 += wdx; sxB1 += wdy;
      sqB0 = fmaf(wc, f.z, sqB0); sqB1 = fmaf(wc, f.w, sqB1);
      mB00 = fmaf(wdx, dx, mB00); mB01 = fmaf(wdx, dy, mB01); mB11 = fmaf(wdy, dy, mB11);
      kB00 = fmaf(wdx, f.z, kB00); kB01 = fmaf(wdx, f.w, kB01);
      kB10 = fmaf(wdy, f.z, kB10); kB11 = fmaf(wdy, f.w, kB11);
    }
  }

  // Epilogue per pixel (IEEE divides kept for numeric fidelity).
  float tA0, tA1, tB0, tB1;
  {
    const float rw = 1.0f / wsA;
    const float d0 = sxA0 * rw, d1 = sxA1 * rw;   // p* - v
    const float q0 = sqA0 * rw, q1 = sqA1 * rw;   // q*
    const float M00 = fmaf(-d0, sxA0, mA00);
    const float M01 = fmaf(-d0, sxA1, mA01);
    const float M11 = fmaf(-d1, sxA1, mA11);
    const float K00 = fmaf(-d0, sqA0, kA00);
    const float K01 = fmaf(-d0, sqA1, kA01);
    const float K10 = fmaf(-d1, sqA0, kA10);
    const float K11 = fmaf(-d1, sqA1, kA11);
    const float det  = fmaf(M00, M11, -M01 * M01);
    const float idet = 1.0f / det;
    const float g0 = -(d0 * M11 - d1 * M01) * idet;
    const float g1 = -(d1 * M00 - d0 * M01) * idet;
    tA0 = fmaf(g0, K00, fmaf(g1, K10, q0));
    tA1 = fmaf(g0, K01, fmaf(g1, K11, q1));
  }
  {
    const float rw = 1.0f / wsB;
    const float d0 = sxB0 * rw, d1 = sxB1 * rw;
    const float q0 = sqB0 * rw, q1 = sqB1 * rw;
    const float M00 = fmaf(-d0, sxB0, mB00);
    const float M01 = fmaf(-d0, sxB1, mB01);
    const float M11 = fmaf(-d1, sxB1, mB11);
    const float K00 = fmaf(-d0, sqB0, kB00);
    const float K01 = fmaf(-d0, sqB1, kB01);
    const float K10 = fmaf(-d1, sqB0, kB10);
    const float K11 = fmaf(-d1, sqB1, kB11);
    const float det  = fmaf(M00, M11, -M01 * M01);
    const float idet = 1.0f / det;
    const float g0 = -(d0 * M11 - d1 * M01) * idet;
    const float g1 = -(d1 * M00 - d0 * M01) * idet;
    tB0 = fmaf(g0, K00, fmaf(g1, K10, q0));
    tB1 = fmaf(g0, K01, fmaf(g1, K11, q1));
  }

  // Out-of-range pixels zeroed (NOT clipped), matching reference.
  if (tA0 < 0.f || tA0 > 31.f) tA0 = 0.f;
  if (tA1 < 0.f || tA1 > 31.f) tA1 = 0.f;
  if (tB0 < 0.f || tB0 > 31.f) tB0 = 0.f;
  if (tB1 < 0.f || tB1 > 31.f) tB1 = 0.f;

  // out layout (B, 2, 32, 32); all 4 stores are coalesced 256-thread runs.
  float* ob = out + b * 2048;
  ob[pixA]               = tA0;
  ob[pixA + 256]         = tB0;
  ob[1024 + pixA]        = tA1;
  ob[1024 + pixA + 256]  = tB1;
}

extern "C" void kernel_launch(void* const* d_in, const int* in_sizes, int n_in,
                              void* d_out, int out_size, void* d_ws, size_t ws_size,
                              hipStream_t stream) {
  const float* sp = (const float*)d_in[0];
  const float* dp = (const float*)d_in[1];
  float* out = (float*)d_out;
  const int B = in_sizes[0] / (NC * 2);   // 512
  mls_kernel<<<dim3(B * 2), dim3(256), 0, stream>>>(sp, dp, out);
}